// Round 1
// baseline (239.320 us; speedup 1.0000x reference)
//
#include <hip/hip_runtime.h>

// GCN 2-layer forward, fp32 in/out, fp16 gather tables. Build: 2-pass MSD
// radix sort by target node. Aggregate: one wave per node, scalar gathers
// (round-11 evidence: >2 unique rows per gather inst regresses — lane map
// keeps all C lanes on one contiguous row), register acc.
// Round-12: h' tables stored fp16 (6.4 MB, 1 line/row) — agg was L2-miss
// bound (FETCH 154 MB vs 12.8 MB table vs 4 MiB/XCD L2). fp32 accumulate;
// error budget ~3e-4 << 4e-3 threshold.
// Round-13: agg was VALU-issue-bound (VALUBusy 66%, HBM 27%). Split the
// hot loop into an unpredicated main loop (no clamp, no mask) + short
// predicated tail; gathers use 32-bit voffset off the uniform table base
// (1 v_lshl_add_u32 per gather, saddr-form global_load_ushort); srcs read
// via per-lane pointer + immediate offsets. ~4 VALU/edge -> ~1 VALU/edge.

#define WAVE 64
#define BN2 512           // nodes per bucket (9 bits local col)
#define NBMAX 256         // max coarse buckets (N <= 131072)
#define CHUNK 8192        // edges per partition block

typedef _Float16 f16;

// ---- bucket count: global histogram of col>>9 ----
__global__ void bucket_count_kernel(const int* __restrict__ col, int* __restrict__ gcnt,
                                    int E, int nb) {
    __shared__ int h[NBMAX];
    for (int i = threadIdx.x; i < nb; i += blockDim.x) h[i] = 0;
    __syncthreads();
    for (int e = blockIdx.x * blockDim.x + threadIdx.x; e < E; e += gridDim.x * blockDim.x)
        atomicAdd(&h[col[e] >> 9], 1);
    __syncthreads();
    for (int i = threadIdx.x; i < nb; i += blockDim.x)
        if (h[i]) atomicAdd(&gcnt[i], h[i]);
}

// ---- exclusive scan of bucket counts -> bptr[nb+1], init gcursor ----
__global__ void bucket_scan_kernel(const int* __restrict__ cnt, int* __restrict__ bptr,
                                   int* __restrict__ gcur, int nb) {
    int lane = threadIdx.x;  // single wave
    int carry = 0;
    for (int base = 0; base < nb; base += WAVE) {
        int i = base + lane;
        int orig = (i < nb) ? cnt[i] : 0;
        int v = orig;
#pragma unroll
        for (int off = 1; off < WAVE; off <<= 1) {
            int t = __shfl_up(v, off, WAVE);
            if (lane >= off) v += t;
        }
        if (i < nb) { bptr[i] = carry + v - orig; gcur[i] = carry + v - orig; }
        carry += __shfl(v, WAVE - 1, WAVE);
    }
    if (lane == 0) bptr[nb] = carry;
}

// ---- pass 1: LDS-binned partition of packed (src<<9 | local_col) ----
__global__ void __launch_bounds__(512)
partition_kernel(const int* __restrict__ row, const int* __restrict__ col,
                 int* __restrict__ gcursor, unsigned* __restrict__ packed,
                 int E, int nb) {
    __shared__ int hist[NBMAX], excl[NBMAX], cursor[NBMAX], baseoff[NBMAX];
    __shared__ unsigned stage[CHUNK];
    int chunk0 = blockIdx.x * CHUNK;
    int cn = E - chunk0; if (cn > CHUNK) cn = CHUNK;
    for (int i = threadIdx.x; i < nb; i += blockDim.x) hist[i] = 0;
    __syncthreads();
    for (int i = threadIdx.x; i < cn; i += blockDim.x)
        atomicAdd(&hist[col[chunk0 + i] >> 9], 1);
    __syncthreads();
    if (threadIdx.x < WAVE) {
        int lane = threadIdx.x, carry = 0;
        for (int base = 0; base < nb; base += WAVE) {
            int i = base + lane;
            int orig = (i < nb) ? hist[i] : 0;
            int v = orig;
#pragma unroll
            for (int off = 1; off < WAVE; off <<= 1) {
                int t = __shfl_up(v, off, WAVE);
                if (lane >= off) v += t;
            }
            if (i < nb) { excl[i] = carry + v - orig; cursor[i] = carry + v - orig; }
            carry += __shfl(v, WAVE - 1, WAVE);
        }
    }
    __syncthreads();
    for (int b = threadIdx.x; b < nb; b += blockDim.x) {
        int c = hist[b];
        baseoff[b] = c ? atomicAdd(&gcursor[b], c) : 0;
    }
    __syncthreads();
    for (int i = threadIdx.x; i < cn; i += blockDim.x) {
        int c = col[chunk0 + i], r = row[chunk0 + i];
        int b = c >> 9;
        int pos = atomicAdd(&cursor[b], 1);
        stage[pos] = ((unsigned)r << 9) | (unsigned)(c & (BN2 - 1));
    }
    __syncthreads();
    int wave = threadIdx.x >> 6, lane = threadIdx.x & 63, nw = blockDim.x >> 6;
    for (int b = wave; b < nb; b += nw) {
        int c = hist[b]; if (!c) continue;
        int s = excl[b], d = baseoff[b];
        for (int k = lane; k < c; k += WAVE) packed[d + k] = stage[s + k];
    }
}

// ---- pass 2: per-bucket sort by local node -> srcs, rowptr, dinv ----
__global__ void __launch_bounds__(512)
sort_kernel(const int* __restrict__ bptr, const unsigned* __restrict__ packed,
            int* __restrict__ srcs, int* __restrict__ rowptr,
            float* __restrict__ dinv, int n, int nb, int E) {
    __shared__ int hist[BN2], excl[BN2], cur[BN2];
    int b = blockIdx.x;
    int start = bptr[b], end = bptr[b + 1];
    for (int i = threadIdx.x; i < BN2; i += blockDim.x) hist[i] = 0;
    __syncthreads();
    for (int k = start + threadIdx.x; k < end; k += blockDim.x)
        atomicAdd(&hist[packed[k] & (BN2 - 1)], 1);
    __syncthreads();
    if (threadIdx.x < WAVE) {
        int lane = threadIdx.x, carry = 0;
#pragma unroll
        for (int base = 0; base < BN2; base += WAVE) {
            int i = base + lane;
            int orig = hist[i];
            int v = orig;
#pragma unroll
            for (int off = 1; off < WAVE; off <<= 1) {
                int t = __shfl_up(v, off, WAVE);
                if (lane >= off) v += t;
            }
            excl[i] = carry + v - orig;
            cur[i]  = carry + v - orig;
            carry += __shfl(v, WAVE - 1, WAVE);
        }
    }
    __syncthreads();
    for (int i = threadIdx.x; i < BN2; i += blockDim.x) {
        int node = b * BN2 + i;
        if (node < n) {
            rowptr[node] = start + excl[i];
            dinv[node]   = hist[i] ? rsqrtf((float)hist[i]) : 0.f;
        }
    }
    if (b == nb - 1 && threadIdx.x == 0) rowptr[n] = E;
    __syncthreads();
    for (int k = start + threadIdx.x; k < end; k += blockDim.x) {
        unsigned p = packed[k];
        int lc = p & (BN2 - 1);
        int pos = atomicAdd(&cur[lc], 1);
        srcs[start + pos] = (int)(p >> 9);
    }
}

// ---- dense: h[n,OUTC] = fp16( (x[n,INC] @ W) * dinv[n] ).
//      Thread = 2 nodes x 4 j. W^T in LDS, stride INC+4 (conflict-free). ----
template <int INC, int OUTC, int JT>
__global__ void __launch_bounds__(256, 4)
dense_kernel(const float* __restrict__ x, const float* __restrict__ W,
             const float* __restrict__ dinv, f16* __restrict__ h, int n) {
    const int LSTR = INC + 4;
    const int SP   = 256 / JT;     // node slots (pairs) per block
    const int NT   = SP * 2;       // nodes per block
    __shared__ float Wt[OUTC * LSTR];
    for (int i = threadIdx.x; i < INC * OUTC; i += 256) {
        int k = i / OUTC, j = i % OUTC;
        Wt[j * LSTR + k] = W[i];
    }
    __syncthreads();
    const int jg = threadIdx.x % JT;
    const int sp = threadIdx.x / JT;
    int base = blockIdx.x * NT;
    int n0 = base + sp;
    int n1 = base + sp + SP;
    int n0c = n0 < n ? n0 : n - 1;   // clamp reads, guard writes
    int n1c = n1 < n ? n1 : n - 1;
    const float4* xr0 = (const float4*)(x + (size_t)n0c * INC);
    const float4* xr1 = (const float4*)(x + (size_t)n1c * INC);
    float a[2][4] = {{0.f, 0.f, 0.f, 0.f}, {0.f, 0.f, 0.f, 0.f}};
#pragma unroll 4
    for (int k4 = 0; k4 < INC / 4; ++k4) {
        float4 v0 = xr0[k4];
        float4 v1 = xr1[k4];
#pragma unroll
        for (int u = 0; u < 4; ++u) {
            float4 w = *(const float4*)(Wt + (jg + u * JT) * LSTR + 4 * k4);
            a[0][u] = fmaf(v0.x, w.x, fmaf(v0.y, w.y, fmaf(v0.z, w.z, fmaf(v0.w, w.w, a[0][u]))));
            a[1][u] = fmaf(v1.x, w.x, fmaf(v1.y, w.y, fmaf(v1.z, w.z, fmaf(v1.w, w.w, a[1][u]))));
        }
    }
    if (n0 < n) {
        float d = dinv[n0];
        f16* hr = h + (size_t)n0 * OUTC;
#pragma unroll
        for (int u = 0; u < 4; ++u) hr[jg + u * JT] = (f16)(a[0][u] * d);
    }
    if (n1 < n) {
        float d = dinv[n1];
        f16* hr = h + (size_t)n1 * OUTC;
#pragma unroll
        for (int u = 0; u < 4; ++u) hr[jg + u * JT] = (f16)(a[1][u] * d);
    }
}

// ---- aggregate: one wave per node; C lanes cover one contiguous fp16 row
//      (64 B = 1 line at C=32); EPW=64/C edges in flight; D=8 batch depth.
//      Main loop unpredicated (full 16-edge blocks), short predicated tail.
//      Gathers: 32-bit voffset + uniform base (saddr global_load_ushort). ----
template <int C, bool RELU>
__global__ void csr_agg_kernel(const int* __restrict__ rowptr, const int* __restrict__ srcs,
                               const float* __restrict__ dinv, const f16* __restrict__ hs,
                               const float* __restrict__ bias, float* __restrict__ out, int n) {
    const int EPW = WAVE / C;       // edges in flight per wave-step
    const int D   = 8;              // batch depth
    const int BLK = D * EPW;        // edges per main-loop iteration
    const int SH  = (C == 32) ? 6 : 5;  // log2(row bytes) = log2(2*C)
    int node = (int)((blockIdx.x * (unsigned)blockDim.x + threadIdx.x) >> 6);
    int lane = threadIdx.x & 63;
    int j  = lane & (C - 1);
    int eo = lane / C;
    if (node >= n) return;
    int start = rowptr[node], end = rowptr[node + 1];
    int deg = end - start;
    int kend = start + (deg & ~(BLK - 1));
    const unsigned j2 = (unsigned)(j << 1);
    const char* hb = (const char*)hs;
    const int* sp = srcs + start + eo;
    float acc0 = 0.f, acc1 = 0.f;
    for (int k = start; k < kend; k += BLK, sp += BLK) {
        int s[D];
#pragma unroll
        for (int u = 0; u < D; ++u)
            s[u] = sp[u * EPW];                 // broadcast loads, imm offsets
        f16 hv[D];
#pragma unroll
        for (int u = 0; u < D; ++u)
            hv[u] = *(const f16*)(hb + (((unsigned)s[u] << SH) + j2));
#pragma unroll
        for (int u = 0; u < D; u += 2) {        // dual chains for ILP
            acc0 += (float)hv[u];
            acc1 += (float)hv[u + 1];
        }
    }
    // tail: deg mod BLK edges, predicated by loop bound only
    for (int k = kend + eo; k < end; k += EPW)
        acc0 += (float)*(const f16*)(hb + (((unsigned)srcs[k] << SH) + j2));
    float acc = acc0 + acc1;
#pragma unroll
    for (int off = C; off < WAVE; off <<= 1)
        acc += __shfl_xor(acc, off, WAVE);
    if (eo == 0) {
        float v = acc * dinv[node] + bias[j];
        if (RELU) v = v > 0.f ? v : 0.f;
        out[(size_t)node * C + j] = v;
    }
}

__global__ void tail_kernel(float* __restrict__ out, int idx) {
    if (blockIdx.x == 0 && threadIdx.x == 0) out[idx] = 0.f;
}

extern "C" void kernel_launch(void* const* d_in, const int* in_sizes, int n_in,
                              void* d_out, int out_size, void* d_ws, size_t ws_size,
                              hipStream_t stream) {
    const float* x  = (const float*)d_in[0];
    const int*   ei = (const int*)d_in[1];    // harness converts int64 -> int32
    const float* W1 = (const float*)d_in[2];
    const float* b1 = (const float*)d_in[3];
    const float* W2 = (const float*)d_in[4];
    const float* b2 = (const float*)d_in[5];

    const int IN_C = 128, HID = 32, OC = 16;
    const int N = in_sizes[0] / IN_C;       // 100000
    const int E = in_sizes[1] / 2;          // 3200000
    const int* row = ei;
    const int* col = ei + E;
    const int NB = (N + BN2 - 1) / BN2;     // 196 coarse buckets

    char* base = (char*)d_ws;
    size_t off = 0;
    auto carve = [&](size_t bytes) -> char* {
        char* p = base + off;
        off = (off + bytes + 255) & ~(size_t)255;
        return p;
    };
    int*      gcnt   = (int*)     carve((size_t)NB * 4);
    int*      bptr   = (int*)     carve((size_t)(NB + 1) * 4);
    int*      gcur   = (int*)     carve((size_t)NB * 4);
    int*      rowptr = (int*)     carve((size_t)(N + 1) * 4);
    float*    dinv   = (float*)   carve((size_t)N * 4);
    unsigned* packed = (unsigned*)carve((size_t)E * 4);
    int*      srcs   = (int*)     carve((size_t)E * 4);
    f16*      hA     = (f16*)     carve((size_t)N * HID * 2);  // h1' then h2' (fp16)
    float*    bufB   = (float*)   carve((size_t)N * HID * 4);  // relu(agg1), fp32
    (void)ws_size; (void)n_in;

    float* outp = (float*)d_out;

    // build: 2-pass coarse radix sort by target node + rowptr + dinv
    hipMemsetAsync(gcnt, 0, (size_t)NB * 4, stream);
    bucket_count_kernel<<<512, 256, 0, stream>>>(col, gcnt, E, NB);
    bucket_scan_kernel<<<1, 64, 0, stream>>>(gcnt, bptr, gcur, NB);
    partition_kernel<<<(E + CHUNK - 1) / CHUNK, 512, 0, stream>>>(row, col, gcur, packed, E, NB);
    sort_kernel<<<NB, 512, 0, stream>>>(bptr, packed, srcs, rowptr, dinv, N, NB, E);

    // layer 1: h1' = fp16((x@W1)*dinv) ; bufB = relu(dinv*agg(h1') + b1)
    {
        const int NT = (256 / 8) * 2;  // 64 nodes per block
        dense_kernel<128, 32, 8><<<(N + NT - 1) / NT, 256, 0, stream>>>(x, W1, dinv, hA, N);
        int nppb = 256 / WAVE;         // 4 nodes per block
        csr_agg_kernel<32, true><<<(N + nppb - 1) / nppb, 256, 0, stream>>>(
            rowptr, srcs, dinv, hA, b1, bufB, N);
    }
    // layer 2: h2' = fp16((bufB@W2)*dinv) ; out = dinv*agg(h2') + b2
    {
        const int NT = (256 / 4) * 2;  // 128 nodes per block
        dense_kernel<32, 16, 4><<<(N + NT - 1) / NT, 256, 0, stream>>>(bufB, W2, dinv, hA, N);
        int nppb = 256 / WAVE;
        csr_agg_kernel<16, false><<<(N + nppb - 1) / nppb, 256, 0, stream>>>(
            rowptr, srcs, dinv, hA, b2, outp, N);
    }
    if (out_size > N * OC)
        tail_kernel<<<1, 64, 0, stream>>>(outp, N * OC);
}

// Round 2
// 233.291 us; speedup vs baseline: 1.0258x; 1.0258x over previous
//
#include <hip/hip_runtime.h>

// GCN 2-layer forward, fp32 in/out, fp16 gather tables. Build: 2-pass MSD
// radix sort by target node -> PADDED CSR (each node's srcs padded to a
// multiple of 16 with a dummy index to a zeroed row). Aggregate: one wave
// per node, C=16 lanes per row (32 B), EPW=4 edges in flight, unpredicated
// main loop with 1-block srcs prefetch, no tail.
// Round-12: fp16 tables (agg was L2-miss bound).
// Round-13 (regressed): tail-split killed MLP — latency-bound, not VALU.
// Round-14: (a) padded CSR — no predication, no serial tail, full-depth
// gathers; (b) layer-1 table split into two 3.2 MB half-tables, aggregated
// in two C=16 passes so every gather table fits the 4 MiB/XCD L2 —
// converts ~900cy HBM-miss gathers into ~200cy L2 hits. Same gather inst
// count as one C=32 pass (E/2 total wave-insts).

#define WAVE 64
#define BN2 512           // nodes per bucket (9 bits local col)
#define NBMAX 256         // max coarse buckets (N <= 131072)
#define CHUNK 8192        // edges per partition block

typedef _Float16 f16;

// ---- bucket count: global histogram of col>>9 ----
__global__ void bucket_count_kernel(const int* __restrict__ col, int* __restrict__ gcnt,
                                    int E, int nb) {
    __shared__ int h[NBMAX];
    for (int i = threadIdx.x; i < nb; i += blockDim.x) h[i] = 0;
    __syncthreads();
    for (int e = blockIdx.x * blockDim.x + threadIdx.x; e < E; e += gridDim.x * blockDim.x)
        atomicAdd(&h[col[e] >> 9], 1);
    __syncthreads();
    for (int i = threadIdx.x; i < nb; i += blockDim.x)
        if (h[i]) atomicAdd(&gcnt[i], h[i]);
}

// ---- exclusive scan of bucket counts -> bptr[nb+1], init gcursor/gpcur,
//      zero the dummy gather rows (row N of each fp16 table) ----
__global__ void bucket_scan_kernel(const int* __restrict__ cnt, int* __restrict__ bptr,
                                   int* __restrict__ gcur, int nb, int* __restrict__ gpcur,
                                   f16* __restrict__ hlo, f16* __restrict__ hhi,
                                   f16* __restrict__ h2t, int nzr) {
    int lane = threadIdx.x;  // single wave
    if (lane == 0) *gpcur = 0;
    if (lane < 16)      hlo[(size_t)nzr * 16 + lane]        = (f16)0.f;
    else if (lane < 32) hhi[(size_t)nzr * 16 + (lane - 16)] = (f16)0.f;
    else if (lane < 48) h2t[(size_t)nzr * 16 + (lane - 32)] = (f16)0.f;
    int carry = 0;
    for (int base = 0; base < nb; base += WAVE) {
        int i = base + lane;
        int orig = (i < nb) ? cnt[i] : 0;
        int v = orig;
#pragma unroll
        for (int off = 1; off < WAVE; off <<= 1) {
            int t = __shfl_up(v, off, WAVE);
            if (lane >= off) v += t;
        }
        if (i < nb) { bptr[i] = carry + v - orig; gcur[i] = carry + v - orig; }
        carry += __shfl(v, WAVE - 1, WAVE);
    }
    if (lane == 0) bptr[nb] = carry;
}

// ---- pass 1: LDS-binned partition of packed (src<<9 | local_col) ----
__global__ void __launch_bounds__(512)
partition_kernel(const int* __restrict__ row, const int* __restrict__ col,
                 int* __restrict__ gcursor, unsigned* __restrict__ packed,
                 int E, int nb) {
    __shared__ int hist[NBMAX], excl[NBMAX], cursor[NBMAX], baseoff[NBMAX];
    __shared__ unsigned stage[CHUNK];
    int chunk0 = blockIdx.x * CHUNK;
    int cn = E - chunk0; if (cn > CHUNK) cn = CHUNK;
    for (int i = threadIdx.x; i < nb; i += blockDim.x) hist[i] = 0;
    __syncthreads();
    for (int i = threadIdx.x; i < cn; i += blockDim.x)
        atomicAdd(&hist[col[chunk0 + i] >> 9], 1);
    __syncthreads();
    if (threadIdx.x < WAVE) {
        int lane = threadIdx.x, carry = 0;
        for (int base = 0; base < nb; base += WAVE) {
            int i = base + lane;
            int orig = (i < nb) ? hist[i] : 0;
            int v = orig;
#pragma unroll
            for (int off = 1; off < WAVE; off <<= 1) {
                int t = __shfl_up(v, off, WAVE);
                if (lane >= off) v += t;
            }
            if (i < nb) { excl[i] = carry + v - orig; cursor[i] = carry + v - orig; }
            carry += __shfl(v, WAVE - 1, WAVE);
        }
    }
    __syncthreads();
    for (int b = threadIdx.x; b < nb; b += blockDim.x) {
        int c = hist[b];
        baseoff[b] = c ? atomicAdd(&gcursor[b], c) : 0;
    }
    __syncthreads();
    for (int i = threadIdx.x; i < cn; i += blockDim.x) {
        int c = col[chunk0 + i], r = row[chunk0 + i];
        int b = c >> 9;
        int pos = atomicAdd(&cursor[b], 1);
        stage[pos] = ((unsigned)r << 9) | (unsigned)(c & (BN2 - 1));
    }
    __syncthreads();
    int wave = threadIdx.x >> 6, lane = threadIdx.x & 63, nw = blockDim.x >> 6;
    for (int b = wave; b < nb; b += nw) {
        int c = hist[b]; if (!c) continue;
        int s = excl[b], d = baseoff[b];
        for (int k = lane; k < c; k += WAVE) packed[d + k] = stage[s + k];
    }
}

// ---- pass 2: per-bucket sort by local node -> padded srcs, pse, dinv.
//      Per-node region padded to multiple of 16; pads point at row n (zeros).
//      Bucket regions allocated via global atomic cursor (order-free). ----
__global__ void __launch_bounds__(512)
sort_kernel(const int* __restrict__ bptr, const unsigned* __restrict__ packed,
            int* __restrict__ srcs, int2* __restrict__ pse,
            float* __restrict__ dinv, int* __restrict__ gpcur,
            int n, int nb, int E) {
    __shared__ int hist[BN2], pex[BN2], cur[BN2];
    __shared__ int pbase_s;
    int b = blockIdx.x;
    int start = bptr[b], end = bptr[b + 1];
    for (int i = threadIdx.x; i < BN2; i += blockDim.x) { hist[i] = 0; cur[i] = 0; }
    __syncthreads();
    for (int k = start + threadIdx.x; k < end; k += blockDim.x)
        atomicAdd(&hist[packed[k] & (BN2 - 1)], 1);
    __syncthreads();
    if (threadIdx.x < WAVE) {   // scan of PADDED degrees over 512 locals
        int lane = threadIdx.x, carry = 0;
#pragma unroll
        for (int base = 0; base < BN2; base += WAVE) {
            int i = base + lane;
            int pd = (hist[i] + 15) & ~15;
            int v = pd;
#pragma unroll
            for (int off = 1; off < WAVE; off <<= 1) {
                int t = __shfl_up(v, off, WAVE);
                if (lane >= off) v += t;
            }
            pex[i] = carry + v - pd;
            carry += __shfl(v, WAVE - 1, WAVE);
        }
        if (lane == 0) pbase_s = atomicAdd(gpcur, carry);
    }
    __syncthreads();
    int pbase = pbase_s;
    for (int i = threadIdx.x; i < BN2; i += blockDim.x) {
        int node = b * BN2 + i;
        if (node < n) {
            int d = hist[i], pd = (d + 15) & ~15;
            int ps = pbase + pex[i];
            pse[node]  = make_int2(ps, ps + pd);
            dinv[node] = d ? rsqrtf((float)d) : 0.f;
            for (int k = d; k < pd; ++k) srcs[ps + k] = n;   // dummy zero-row
        }
    }
    __syncthreads();
    for (int k = start + threadIdx.x; k < end; k += blockDim.x) {
        unsigned p = packed[k];
        int lc = p & (BN2 - 1);
        int pos = atomicAdd(&cur[lc], 1);
        srcs[pbase + pex[lc] + pos] = (int)(p >> 9);
    }
}

// ---- dense: h[n,OUTC] = fp16( (x[n,INC] @ W) * dinv[n] ).
//      Thread = 2 nodes x 4 j. W^T in LDS, stride INC+4 (conflict-free).
//      SPLIT: route cols 0-15 -> hlo, 16-31 -> hhi (16-wide fp16 rows). ----
template <int INC, int OUTC, int JT, bool SPLIT>
__global__ void __launch_bounds__(256, 4)
dense_kernel(const float* __restrict__ x, const float* __restrict__ W,
             const float* __restrict__ dinv, f16* __restrict__ hlo,
             f16* __restrict__ hhi, int n) {
    const int LSTR = INC + 4;
    const int SP   = 256 / JT;     // node slots (pairs) per block
    const int NT   = SP * 2;       // nodes per block
    __shared__ float Wt[OUTC * LSTR];
    for (int i = threadIdx.x; i < INC * OUTC; i += 256) {
        int k = i / OUTC, j = i % OUTC;
        Wt[j * LSTR + k] = W[i];
    }
    __syncthreads();
    const int jg = threadIdx.x % JT;
    const int sp = threadIdx.x / JT;
    int base = blockIdx.x * NT;
    int n0 = base + sp;
    int n1 = base + sp + SP;
    int n0c = n0 < n ? n0 : n - 1;   // clamp reads, guard writes
    int n1c = n1 < n ? n1 : n - 1;
    const float4* xr0 = (const float4*)(x + (size_t)n0c * INC);
    const float4* xr1 = (const float4*)(x + (size_t)n1c * INC);
    float a[2][4] = {{0.f, 0.f, 0.f, 0.f}, {0.f, 0.f, 0.f, 0.f}};
#pragma unroll 4
    for (int k4 = 0; k4 < INC / 4; ++k4) {
        float4 v0 = xr0[k4];
        float4 v1 = xr1[k4];
#pragma unroll
        for (int u = 0; u < 4; ++u) {
            float4 w = *(const float4*)(Wt + (jg + u * JT) * LSTR + 4 * k4);
            a[0][u] = fmaf(v0.x, w.x, fmaf(v0.y, w.y, fmaf(v0.z, w.z, fmaf(v0.w, w.w, a[0][u]))));
            a[1][u] = fmaf(v1.x, w.x, fmaf(v1.y, w.y, fmaf(v1.z, w.z, fmaf(v1.w, w.w, a[1][u]))));
        }
    }
#pragma unroll
    for (int pair = 0; pair < 2; ++pair) {
        int nn = pair ? n1 : n0;
        if (nn < n) {
            float d = dinv[nn];
#pragma unroll
            for (int u = 0; u < 4; ++u) {
                int c = jg + u * JT;
                f16* t;
                if (SPLIT) t = (c < 16) ? (hlo + (size_t)nn * 16 + c)
                               : (hhi + (size_t)nn * 16 + (c - 16));
                else       t = hlo + (size_t)nn * OUTC + c;
                *t = (f16)(a[pair][u] * d);
            }
        }
    }
}

// ---- aggregate: one wave per node; 16 lanes cover one 32 B fp16 row;
//      EPW=4 rows in flight; padded CSR -> unpredicated, no tail; srcs
//      prefetched one block ahead (64 B overread into padded workspace). ----
template <bool RELU>
__global__ void csr_agg16_kernel(const int2* __restrict__ pse, const int* __restrict__ srcs,
                                 const float* __restrict__ dinv, const f16* __restrict__ hs,
                                 const float* __restrict__ bias, float* __restrict__ out,
                                 int ostride, int ocol, int n) {
    int node = (int)((blockIdx.x * (unsigned)blockDim.x + threadIdx.x) >> 6);
    int lane = threadIdx.x & 63;
    int j  = lane & 15;
    int eo = lane >> 4;           // 0..3
    if (node >= n) return;
    int2 se = pse[node];
    int start = se.x, end = se.y; // (end-start) % 16 == 0
    const unsigned j2 = (unsigned)(j << 1);
    const char* hb = (const char*)hs;
    const int* sp = srcs + start + eo;
    float acc0 = 0.f, acc1 = 0.f;
    int s0 = sp[0], s1 = sp[4], s2 = sp[8], s3 = sp[12];
    for (int k = start; k < end; k += 16) {
        sp += 16;
        int t0 = sp[0], t1 = sp[4], t2 = sp[8], t3 = sp[12];  // prefetch next
        f16 h0 = *(const f16*)(hb + (((unsigned)s0 << 5) + j2));
        f16 h1 = *(const f16*)(hb + (((unsigned)s1 << 5) + j2));
        f16 h2 = *(const f16*)(hb + (((unsigned)s2 << 5) + j2));
        f16 h3 = *(const f16*)(hb + (((unsigned)s3 << 5) + j2));
        acc0 += (float)h0; acc1 += (float)h1;
        acc0 += (float)h2; acc1 += (float)h3;
        s0 = t0; s1 = t1; s2 = t2; s3 = t3;
    }
    float acc = acc0 + acc1;
    acc += __shfl_xor(acc, 16, WAVE);
    acc += __shfl_xor(acc, 32, WAVE);
    if (eo == 0) {
        float v = acc * dinv[node] + bias[j];
        if (RELU) v = v > 0.f ? v : 0.f;
        out[(size_t)node * ostride + ocol + j] = v;
    }
}

__global__ void tail_kernel(float* __restrict__ out, int idx) {
    if (blockIdx.x == 0 && threadIdx.x == 0) out[idx] = 0.f;
}

extern "C" void kernel_launch(void* const* d_in, const int* in_sizes, int n_in,
                              void* d_out, int out_size, void* d_ws, size_t ws_size,
                              hipStream_t stream) {
    const float* x  = (const float*)d_in[0];
    const int*   ei = (const int*)d_in[1];    // harness converts int64 -> int32
    const float* W1 = (const float*)d_in[2];
    const float* b1 = (const float*)d_in[3];
    const float* W2 = (const float*)d_in[4];
    const float* b2 = (const float*)d_in[5];

    const int IN_C = 128, HID = 32, OC = 16;
    const int N = in_sizes[0] / IN_C;       // 100000
    const int E = in_sizes[1] / 2;          // 3200000
    const int* row = ei;
    const int* col = ei + E;
    const int NB = (N + BN2 - 1) / BN2;     // 196 coarse buckets

    char* base = (char*)d_ws;
    size_t off = 0;
    auto carve = [&](size_t bytes) -> char* {
        char* p = base + off;
        off = (off + bytes + 255) & ~(size_t)255;
        return p;
    };
    int*      gcnt  = (int*)     carve((size_t)NB * 4);
    int*      bptr  = (int*)     carve((size_t)(NB + 1) * 4);
    int*      gcur  = (int*)     carve((size_t)NB * 4);
    int*      gpcur = (int*)     carve(4);
    float*    dinv  = (float*)   carve((size_t)N * 4);
    int2*     pse   = (int2*)    carve((size_t)N * 8);
    unsigned* packed= (unsigned*)carve((size_t)E * 4);
    int*      srcsP = (int*)     carve(((size_t)E + (size_t)N * 16 + 16) * 4); // padded + overread
    f16*      hlo   = (f16*)     carve((size_t)(N + 1) * 16 * 2);  // layer1 cols 0-15 (+zero row)
    f16*      hhi   = (f16*)     carve((size_t)(N + 1) * 16 * 2);  // layer1 cols 16-31
    f16*      h2t   = (f16*)     carve((size_t)(N + 1) * 16 * 2);  // layer2 table
    float*    bufB  = (float*)   carve((size_t)N * HID * 4);       // relu(agg1), fp32
    (void)ws_size; (void)n_in;

    float* outp = (float*)d_out;

    // build: 2-pass coarse radix sort by target node -> padded CSR + dinv
    hipMemsetAsync(gcnt, 0, (size_t)NB * 4, stream);
    bucket_count_kernel<<<512, 256, 0, stream>>>(col, gcnt, E, NB);
    bucket_scan_kernel<<<1, 64, 0, stream>>>(gcnt, bptr, gcur, NB, gpcur, hlo, hhi, h2t, N);
    partition_kernel<<<(E + CHUNK - 1) / CHUNK, 512, 0, stream>>>(row, col, gcur, packed, E, NB);
    sort_kernel<<<NB, 512, 0, stream>>>(bptr, packed, srcsP, pse, dinv, gpcur, N, NB, E);

    int nppb = 256 / WAVE;  // 4 nodes per block
    int ngrid = (N + nppb - 1) / nppb;

    // layer 1: {hlo,hhi} = fp16((x@W1)*dinv) ; bufB = relu(dinv*agg + b1)
    {
        const int NT = (256 / 8) * 2;  // 64 nodes per block
        dense_kernel<128, 32, 8, true><<<(N + NT - 1) / NT, 256, 0, stream>>>(x, W1, dinv, hlo, hhi, N);
        csr_agg16_kernel<true><<<ngrid, 256, 0, stream>>>(pse, srcsP, dinv, hlo, b1,      bufB, HID, 0,  N);
        csr_agg16_kernel<true><<<ngrid, 256, 0, stream>>>(pse, srcsP, dinv, hhi, b1 + 16, bufB, HID, 16, N);
    }
    // layer 2: h2t = fp16((bufB@W2)*dinv) ; out = dinv*agg(h2t) + b2
    {
        const int NT = (256 / 4) * 2;  // 128 nodes per block
        dense_kernel<32, 16, 4, false><<<(N + NT - 1) / NT, 256, 0, stream>>>(bufB, W2, dinv, h2t, nullptr, N);
        csr_agg16_kernel<false><<<ngrid, 256, 0, stream>>>(pse, srcsP, dinv, h2t, b2, outp, OC, 0, N);
    }
    if (out_size > N * OC)
        tail_kernel<<<1, 64, 0, stream>>>(outp, N * OC);
}

// Round 3
// 228.403 us; speedup vs baseline: 1.0478x; 1.0214x over previous
//
#include <hip/hip_runtime.h>

// GCN 2-layer forward, fp32 in/out, fp16 gather tables. Build: 2-pass MSD
// radix sort by target node -> PADDED CSR (each node's srcs padded to a
// multiple of 16 with a dummy index to a zeroed row). Aggregate: one wave
// per node, C=16 lanes per row (32 B), 4 edge slots, 2-block register
// rotation: gathers issued one block ahead, srcs prefetched two blocks
// ahead -> 8 loads in flight per wave (counted vmcnt), no predication.
// Round-12: fp16 tables (agg was L2-miss bound at fp32).
// Round-13 (regressed): tail-split killed MLP — latency-bound, not VALU.
// Round-14: padded CSR + split layer-1 tables (3.2 MB, L2-resident):
// FETCH 101->29 MB/pass but time flat — gathers only 4-deep, MLP-bound.
// Round-15: 2-block rotation restores 8-deep pipelining on the L2-hit
// path; layer-1 stays two C=16 passes (fusing both halves would put
// 6.4 MB in one pass's working set > 4 MiB/XCD L2).

#define WAVE 64
#define BN2 512           // nodes per bucket (9 bits local col)
#define NBMAX 256         // max coarse buckets (N <= 131072)
#define CHUNK 8192        // edges per partition block

typedef _Float16 f16;

// ---- bucket count: global histogram of col>>9 ----
__global__ void bucket_count_kernel(const int* __restrict__ col, int* __restrict__ gcnt,
                                    int E, int nb) {
    __shared__ int h[NBMAX];
    for (int i = threadIdx.x; i < nb; i += blockDim.x) h[i] = 0;
    __syncthreads();
    for (int e = blockIdx.x * blockDim.x + threadIdx.x; e < E; e += gridDim.x * blockDim.x)
        atomicAdd(&h[col[e] >> 9], 1);
    __syncthreads();
    for (int i = threadIdx.x; i < nb; i += blockDim.x)
        if (h[i]) atomicAdd(&gcnt[i], h[i]);
}

// ---- exclusive scan of bucket counts -> bptr[nb+1], init gcursor/gpcur,
//      zero the dummy gather rows (row N of each fp16 table) ----
__global__ void bucket_scan_kernel(const int* __restrict__ cnt, int* __restrict__ bptr,
                                   int* __restrict__ gcur, int nb, int* __restrict__ gpcur,
                                   f16* __restrict__ hlo, f16* __restrict__ hhi,
                                   f16* __restrict__ h2t, int nzr) {
    int lane = threadIdx.x;  // single wave
    if (lane == 0) *gpcur = 0;
    if (lane < 16)      hlo[(size_t)nzr * 16 + lane]        = (f16)0.f;
    else if (lane < 32) hhi[(size_t)nzr * 16 + (lane - 16)] = (f16)0.f;
    else if (lane < 48) h2t[(size_t)nzr * 16 + (lane - 32)] = (f16)0.f;
    int carry = 0;
    for (int base = 0; base < nb; base += WAVE) {
        int i = base + lane;
        int orig = (i < nb) ? cnt[i] : 0;
        int v = orig;
#pragma unroll
        for (int off = 1; off < WAVE; off <<= 1) {
            int t = __shfl_up(v, off, WAVE);
            if (lane >= off) v += t;
        }
        if (i < nb) { bptr[i] = carry + v - orig; gcur[i] = carry + v - orig; }
        carry += __shfl(v, WAVE - 1, WAVE);
    }
    if (lane == 0) bptr[nb] = carry;
}

// ---- pass 1: LDS-binned partition of packed (src<<9 | local_col) ----
__global__ void __launch_bounds__(512)
partition_kernel(const int* __restrict__ row, const int* __restrict__ col,
                 int* __restrict__ gcursor, unsigned* __restrict__ packed,
                 int E, int nb) {
    __shared__ int hist[NBMAX], excl[NBMAX], cursor[NBMAX], baseoff[NBMAX];
    __shared__ unsigned stage[CHUNK];
    int chunk0 = blockIdx.x * CHUNK;
    int cn = E - chunk0; if (cn > CHUNK) cn = CHUNK;
    for (int i = threadIdx.x; i < nb; i += blockDim.x) hist[i] = 0;
    __syncthreads();
    for (int i = threadIdx.x; i < cn; i += blockDim.x)
        atomicAdd(&hist[col[chunk0 + i] >> 9], 1);
    __syncthreads();
    if (threadIdx.x < WAVE) {
        int lane = threadIdx.x, carry = 0;
        for (int base = 0; base < nb; base += WAVE) {
            int i = base + lane;
            int orig = (i < nb) ? hist[i] : 0;
            int v = orig;
#pragma unroll
            for (int off = 1; off < WAVE; off <<= 1) {
                int t = __shfl_up(v, off, WAVE);
                if (lane >= off) v += t;
            }
            if (i < nb) { excl[i] = carry + v - orig; cursor[i] = carry + v - orig; }
            carry += __shfl(v, WAVE - 1, WAVE);
        }
    }
    __syncthreads();
    for (int b = threadIdx.x; b < nb; b += blockDim.x) {
        int c = hist[b];
        baseoff[b] = c ? atomicAdd(&gcursor[b], c) : 0;
    }
    __syncthreads();
    for (int i = threadIdx.x; i < cn; i += blockDim.x) {
        int c = col[chunk0 + i], r = row[chunk0 + i];
        int b = c >> 9;
        int pos = atomicAdd(&cursor[b], 1);
        stage[pos] = ((unsigned)r << 9) | (unsigned)(c & (BN2 - 1));
    }
    __syncthreads();
    int wave = threadIdx.x >> 6, lane = threadIdx.x & 63, nw = blockDim.x >> 6;
    for (int b = wave; b < nb; b += nw) {
        int c = hist[b]; if (!c) continue;
        int s = excl[b], d = baseoff[b];
        for (int k = lane; k < c; k += WAVE) packed[d + k] = stage[s + k];
    }
}

// ---- pass 2: per-bucket sort by local node -> padded srcs, pse, dinv.
//      Per-node region padded to multiple of 16; pads point at row n (zeros).
//      Bucket regions allocated via global atomic cursor (order-free). ----
__global__ void __launch_bounds__(512)
sort_kernel(const int* __restrict__ bptr, const unsigned* __restrict__ packed,
            int* __restrict__ srcs, int2* __restrict__ pse,
            float* __restrict__ dinv, int* __restrict__ gpcur,
            int n, int nb, int E) {
    __shared__ int hist[BN2], pex[BN2], cur[BN2];
    __shared__ int pbase_s;
    int b = blockIdx.x;
    int start = bptr[b], end = bptr[b + 1];
    for (int i = threadIdx.x; i < BN2; i += blockDim.x) { hist[i] = 0; cur[i] = 0; }
    __syncthreads();
    for (int k = start + threadIdx.x; k < end; k += blockDim.x)
        atomicAdd(&hist[packed[k] & (BN2 - 1)], 1);
    __syncthreads();
    if (threadIdx.x < WAVE) {   // scan of PADDED degrees over 512 locals
        int lane = threadIdx.x, carry = 0;
#pragma unroll
        for (int base = 0; base < BN2; base += WAVE) {
            int i = base + lane;
            int pd = (hist[i] + 15) & ~15;
            int v = pd;
#pragma unroll
            for (int off = 1; off < WAVE; off <<= 1) {
                int t = __shfl_up(v, off, WAVE);
                if (lane >= off) v += t;
            }
            pex[i] = carry + v - pd;
            carry += __shfl(v, WAVE - 1, WAVE);
        }
        if (lane == 0) pbase_s = atomicAdd(gpcur, carry);
    }
    __syncthreads();
    int pbase = pbase_s;
    for (int i = threadIdx.x; i < BN2; i += blockDim.x) {
        int node = b * BN2 + i;
        if (node < n) {
            int d = hist[i], pd = (d + 15) & ~15;
            int ps = pbase + pex[i];
            pse[node]  = make_int2(ps, ps + pd);
            dinv[node] = d ? rsqrtf((float)d) : 0.f;
            for (int k = d; k < pd; ++k) srcs[ps + k] = n;   // dummy zero-row
        }
    }
    __syncthreads();
    for (int k = start + threadIdx.x; k < end; k += blockDim.x) {
        unsigned p = packed[k];
        int lc = p & (BN2 - 1);
        int pos = atomicAdd(&cur[lc], 1);
        srcs[pbase + pex[lc] + pos] = (int)(p >> 9);
    }
}

// ---- dense: h[n,OUTC] = fp16( (x[n,INC] @ W) * dinv[n] ).
//      Thread = 2 nodes x 4 j. W^T in LDS, stride INC+4 (conflict-free).
//      SPLIT: route cols 0-15 -> hlo, 16-31 -> hhi (16-wide fp16 rows). ----
template <int INC, int OUTC, int JT, bool SPLIT>
__global__ void __launch_bounds__(256, 4)
dense_kernel(const float* __restrict__ x, const float* __restrict__ W,
             const float* __restrict__ dinv, f16* __restrict__ hlo,
             f16* __restrict__ hhi, int n) {
    const int LSTR = INC + 4;
    const int SP   = 256 / JT;     // node slots (pairs) per block
    const int NT   = SP * 2;       // nodes per block
    __shared__ float Wt[OUTC * LSTR];
    for (int i = threadIdx.x; i < INC * OUTC; i += 256) {
        int k = i / OUTC, j = i % OUTC;
        Wt[j * LSTR + k] = W[i];
    }
    __syncthreads();
    const int jg = threadIdx.x % JT;
    const int sp = threadIdx.x / JT;
    int base = blockIdx.x * NT;
    int n0 = base + sp;
    int n1 = base + sp + SP;
    int n0c = n0 < n ? n0 : n - 1;   // clamp reads, guard writes
    int n1c = n1 < n ? n1 : n - 1;
    const float4* xr0 = (const float4*)(x + (size_t)n0c * INC);
    const float4* xr1 = (const float4*)(x + (size_t)n1c * INC);
    float a[2][4] = {{0.f, 0.f, 0.f, 0.f}, {0.f, 0.f, 0.f, 0.f}};
#pragma unroll 4
    for (int k4 = 0; k4 < INC / 4; ++k4) {
        float4 v0 = xr0[k4];
        float4 v1 = xr1[k4];
#pragma unroll
        for (int u = 0; u < 4; ++u) {
            float4 w = *(const float4*)(Wt + (jg + u * JT) * LSTR + 4 * k4);
            a[0][u] = fmaf(v0.x, w.x, fmaf(v0.y, w.y, fmaf(v0.z, w.z, fmaf(v0.w, w.w, a[0][u]))));
            a[1][u] = fmaf(v1.x, w.x, fmaf(v1.y, w.y, fmaf(v1.z, w.z, fmaf(v1.w, w.w, a[1][u]))));
        }
    }
#pragma unroll
    for (int pair = 0; pair < 2; ++pair) {
        int nn = pair ? n1 : n0;
        if (nn < n) {
            float d = dinv[nn];
#pragma unroll
            for (int u = 0; u < 4; ++u) {
                int c = jg + u * JT;
                f16* t;
                if (SPLIT) t = (c < 16) ? (hlo + (size_t)nn * 16 + c)
                               : (hhi + (size_t)nn * 16 + (c - 16));
                else       t = hlo + (size_t)nn * OUTC + c;
                *t = (f16)(a[pair][u] * d);
            }
        }
    }
}

// ---- aggregate: one wave per node; 16 lanes cover one 32 B fp16 row;
//      4 edge slots; 2-block register rotation: gathers for block b+1 and
//      srcs for block b+2 issued before consuming block b -> 8 loads in
//      flight (compiler emits counted vmcnt). Padded CSR: no predication,
//      all prefetches clamped inside the node's own padded region. ----
template <bool RELU>
__global__ void csr_agg16_kernel(const int2* __restrict__ pse, const int* __restrict__ srcs,
                                 const float* __restrict__ dinv, const f16* __restrict__ hs,
                                 const float* __restrict__ bias, float* __restrict__ out,
                                 int ostride, int ocol, int n) {
    int node = (int)((blockIdx.x * (unsigned)blockDim.x + threadIdx.x) >> 6);
    int lane = threadIdx.x & 63;
    int j  = lane & 15;
    int eo = lane >> 4;           // 0..3
    if (node >= n) return;
    int2 se = pse[node];
    int start = se.x;
    int nb = (se.y - se.x) >> 4;  // padded 16-edge blocks
    float bj = bias[ocol + j];
    float dv = dinv[node];
    if (nb == 0) {
        if (eo == 0) {
            float v = bj;
            if (RELU) v = v > 0.f ? v : 0.f;
            out[(size_t)node * ostride + ocol + j] = v;
        }
        return;
    }
    const unsigned j2 = (unsigned)(j << 1);
    const char* hb = (const char*)hs;
    const int* sp = srcs + start + eo;
    // prologue: block 0 srcs -> gathers; block 1 srcs (clamped)
    int sA0 = sp[0], sA1 = sp[4], sA2 = sp[8], sA3 = sp[12];
    f16 hA0 = *(const f16*)(hb + (((unsigned)sA0 << 5) + j2));
    f16 hA1 = *(const f16*)(hb + (((unsigned)sA1 << 5) + j2));
    f16 hA2 = *(const f16*)(hb + (((unsigned)sA2 << 5) + j2));
    f16 hA3 = *(const f16*)(hb + (((unsigned)sA3 << 5) + j2));
    const int* sp1 = sp + (nb > 1 ? 16 : 0);
    int sB0 = sp1[0], sB1 = sp1[4], sB2 = sp1[8], sB3 = sp1[12];
    float acc0 = 0.f, acc1 = 0.f;
    for (int b = 0; b < nb - 1; ++b) {
        // issue gathers for block b+1
        f16 g0 = *(const f16*)(hb + (((unsigned)sB0 << 5) + j2));
        f16 g1 = *(const f16*)(hb + (((unsigned)sB1 << 5) + j2));
        f16 g2 = *(const f16*)(hb + (((unsigned)sB2 << 5) + j2));
        f16 g3 = *(const f16*)(hb + (((unsigned)sB3 << 5) + j2));
        // prefetch srcs for block b+2 (clamped to last block)
        int nxt = b + 2; nxt = nxt < nb ? nxt : nb - 1;
        const int* spn = sp + nxt * 16;
        int t0 = spn[0], t1 = spn[4], t2 = spn[8], t3 = spn[12];
        // consume block b (waits only the 4 oldest loads)
        acc0 += (float)hA0; acc1 += (float)hA1;
        acc0 += (float)hA2; acc1 += (float)hA3;
        hA0 = g0; hA1 = g1; hA2 = g2; hA3 = g3;
        sB0 = t0; sB1 = t1; sB2 = t2; sB3 = t3;
    }
    acc0 += (float)hA0; acc1 += (float)hA1;
    acc0 += (float)hA2; acc1 += (float)hA3;
    float acc = acc0 + acc1;
    acc += __shfl_xor(acc, 16, WAVE);
    acc += __shfl_xor(acc, 32, WAVE);
    if (eo == 0) {
        float v = acc * dv + bj;
        if (RELU) v = v > 0.f ? v : 0.f;
        out[(size_t)node * ostride + ocol + j] = v;
    }
}

__global__ void tail_kernel(float* __restrict__ out, int idx) {
    if (blockIdx.x == 0 && threadIdx.x == 0) out[idx] = 0.f;
}

extern "C" void kernel_launch(void* const* d_in, const int* in_sizes, int n_in,
                              void* d_out, int out_size, void* d_ws, size_t ws_size,
                              hipStream_t stream) {
    const float* x  = (const float*)d_in[0];
    const int*   ei = (const int*)d_in[1];    // harness converts int64 -> int32
    const float* W1 = (const float*)d_in[2];
    const float* b1 = (const float*)d_in[3];
    const float* W2 = (const float*)d_in[4];
    const float* b2 = (const float*)d_in[5];

    const int IN_C = 128, HID = 32, OC = 16;
    const int N = in_sizes[0] / IN_C;       // 100000
    const int E = in_sizes[1] / 2;          // 3200000
    const int* row = ei;
    const int* col = ei + E;
    const int NB = (N + BN2 - 1) / BN2;     // 196 coarse buckets

    char* base = (char*)d_ws;
    size_t off = 0;
    auto carve = [&](size_t bytes) -> char* {
        char* p = base + off;
        off = (off + bytes + 255) & ~(size_t)255;
        return p;
    };
    int*      gcnt  = (int*)     carve((size_t)NB * 4);
    int*      bptr  = (int*)     carve((size_t)(NB + 1) * 4);
    int*      gcur  = (int*)     carve((size_t)NB * 4);
    int*      gpcur = (int*)     carve(4);
    float*    dinv  = (float*)   carve((size_t)N * 4);
    int2*     pse   = (int2*)    carve((size_t)N * 8);
    unsigned* packed= (unsigned*)carve((size_t)E * 4);
    int*      srcsP = (int*)     carve(((size_t)E + (size_t)N * 16 + 16) * 4); // padded + overread
    f16*      hlo   = (f16*)     carve((size_t)(N + 1) * 16 * 2);  // layer1 cols 0-15 (+zero row)
    f16*      hhi   = (f16*)     carve((size_t)(N + 1) * 16 * 2);  // layer1 cols 16-31
    f16*      h2t   = (f16*)     carve((size_t)(N + 1) * 16 * 2);  // layer2 table
    float*    bufB  = (float*)   carve((size_t)N * HID * 4);       // relu(agg1), fp32
    (void)ws_size; (void)n_in;

    float* outp = (float*)d_out;

    // build: 2-pass coarse radix sort by target node -> padded CSR + dinv
    hipMemsetAsync(gcnt, 0, (size_t)NB * 4, stream);
    bucket_count_kernel<<<512, 256, 0, stream>>>(col, gcnt, E, NB);
    bucket_scan_kernel<<<1, 64, 0, stream>>>(gcnt, bptr, gcur, NB, gpcur, hlo, hhi, h2t, N);
    partition_kernel<<<(E + CHUNK - 1) / CHUNK, 512, 0, stream>>>(row, col, gcur, packed, E, NB);
    sort_kernel<<<NB, 512, 0, stream>>>(bptr, packed, srcsP, pse, dinv, gpcur, N, NB, E);

    int nppb = 256 / WAVE;  // 4 nodes per block
    int ngrid = (N + nppb - 1) / nppb;

    // layer 1: {hlo,hhi} = fp16((x@W1)*dinv) ; bufB = relu(dinv*agg + b1)
    {
        const int NT = (256 / 8) * 2;  // 64 nodes per block
        dense_kernel<128, 32, 8, true><<<(N + NT - 1) / NT, 256, 0, stream>>>(x, W1, dinv, hlo, hhi, N);
        csr_agg16_kernel<true><<<ngrid, 256, 0, stream>>>(pse, srcsP, dinv, hlo, b1,      bufB, HID, 0,  N);
        csr_agg16_kernel<true><<<ngrid, 256, 0, stream>>>(pse, srcsP, dinv, hhi, b1 + 16, bufB, HID, 16, N);
    }
    // layer 2: h2t = fp16((bufB@W2)*dinv) ; out = dinv*agg(h2t) + b2
    {
        const int NT = (256 / 4) * 2;  // 128 nodes per block
        dense_kernel<32, 16, 4, false><<<(N + NT - 1) / NT, 256, 0, stream>>>(bufB, W2, dinv, h2t, nullptr, N);
        csr_agg16_kernel<false><<<ngrid, 256, 0, stream>>>(pse, srcsP, dinv, h2t, b2, outp, OC, 0, N);
    }
    if (out_size > N * OC)
        tail_kernel<<<1, 64, 0, stream>>>(outp, N * OC);
}

// Round 4
// 196.819 us; speedup vs baseline: 1.2159x; 1.1605x over previous
//
#include <hip/hip_runtime.h>

// GCN 2-layer forward, fp32 in/out, fp16 gather tables. Build: 2-pass MSD
// radix sort by target node -> PADDED CSR (each node's srcs padded to a
// multiple of 16 with a dummy index to a zeroed row; zero-degree nodes get
// pse=(0,0) so clamped reads stay in initialized memory). Aggregate: one
// wave per TWO nodes, C=16 lanes per row (32 B), 2-block register rotation
// -> 16 gathers + 8 srcs in flight per wave; per-node mask/clamp (no tail).
// Round-12: fp16 tables (agg was L2-miss bound at fp32).
// Round-13 (regressed): tail-split killed MLP — latency-bound, not VALU.
// Round-14: padded CSR + split layer-1 tables (3.2 MB, L2-resident):
// FETCH 101->29 MB/pass but time flat — gathers only 4-deep, MLP-bound.
// Round-15: 2-block rotation (8 in flight): all aggs < 38 us.
// Round-16: 2 nodes/wave (doubles independent chains; serial pse->srcs->
// gather chain was the limiter at 1 node/wave), lo+hi passes fused into
// one launch, tail folded into agg2.

#define WAVE 64
#define BN2 512           // nodes per bucket (9 bits local col)
#define NBMAX 256         // max coarse buckets (N <= 131072)
#define CHUNK 8192        // edges per partition block

typedef _Float16 f16;

// ---- bucket count: global histogram of col>>9 ----
__global__ void bucket_count_kernel(const int* __restrict__ col, int* __restrict__ gcnt,
                                    int E, int nb) {
    __shared__ int h[NBMAX];
    for (int i = threadIdx.x; i < nb; i += blockDim.x) h[i] = 0;
    __syncthreads();
    for (int e = blockIdx.x * blockDim.x + threadIdx.x; e < E; e += gridDim.x * blockDim.x)
        atomicAdd(&h[col[e] >> 9], 1);
    __syncthreads();
    for (int i = threadIdx.x; i < nb; i += blockDim.x)
        if (h[i]) atomicAdd(&gcnt[i], h[i]);
}

// ---- exclusive scan of bucket counts -> bptr[nb+1], init gcursor/gpcur,
//      zero the dummy gather rows (row N of each fp16 table) ----
__global__ void bucket_scan_kernel(const int* __restrict__ cnt, int* __restrict__ bptr,
                                   int* __restrict__ gcur, int nb, int* __restrict__ gpcur,
                                   f16* __restrict__ hlo, f16* __restrict__ hhi,
                                   f16* __restrict__ h2t, int nzr) {
    int lane = threadIdx.x;  // single wave
    if (lane < 2) gpcur[lane] = 0;
    if (lane < 16)      hlo[(size_t)nzr * 16 + lane]        = (f16)0.f;
    else if (lane < 32) hhi[(size_t)nzr * 16 + (lane - 16)] = (f16)0.f;
    else if (lane < 48) h2t[(size_t)nzr * 16 + (lane - 32)] = (f16)0.f;
    int carry = 0;
    for (int base = 0; base < nb; base += WAVE) {
        int i = base + lane;
        int orig = (i < nb) ? cnt[i] : 0;
        int v = orig;
#pragma unroll
        for (int off = 1; off < WAVE; off <<= 1) {
            int t = __shfl_up(v, off, WAVE);
            if (lane >= off) v += t;
        }
        if (i < nb) { bptr[i] = carry + v - orig; gcur[i] = carry + v - orig; }
        carry += __shfl(v, WAVE - 1, WAVE);
    }
    if (lane == 0) bptr[nb] = carry;
}

// ---- pass 1: LDS-binned partition of packed (src<<9 | local_col) ----
__global__ void __launch_bounds__(512)
partition_kernel(const int* __restrict__ row, const int* __restrict__ col,
                 int* __restrict__ gcursor, unsigned* __restrict__ packed,
                 int E, int nb) {
    __shared__ int hist[NBMAX], excl[NBMAX], cursor[NBMAX], baseoff[NBMAX];
    __shared__ unsigned stage[CHUNK];
    int chunk0 = blockIdx.x * CHUNK;
    int cn = E - chunk0; if (cn > CHUNK) cn = CHUNK;
    for (int i = threadIdx.x; i < nb; i += blockDim.x) hist[i] = 0;
    __syncthreads();
    for (int i = threadIdx.x; i < cn; i += blockDim.x)
        atomicAdd(&hist[col[chunk0 + i] >> 9], 1);
    __syncthreads();
    if (threadIdx.x < WAVE) {
        int lane = threadIdx.x, carry = 0;
        for (int base = 0; base < nb; base += WAVE) {
            int i = base + lane;
            int orig = (i < nb) ? hist[i] : 0;
            int v = orig;
#pragma unroll
            for (int off = 1; off < WAVE; off <<= 1) {
                int t = __shfl_up(v, off, WAVE);
                if (lane >= off) v += t;
            }
            if (i < nb) { excl[i] = carry + v - orig; cursor[i] = carry + v - orig; }
            carry += __shfl(v, WAVE - 1, WAVE);
        }
    }
    __syncthreads();
    for (int b = threadIdx.x; b < nb; b += blockDim.x) {
        int c = hist[b];
        baseoff[b] = c ? atomicAdd(&gcursor[b], c) : 0;
    }
    __syncthreads();
    for (int i = threadIdx.x; i < cn; i += blockDim.x) {
        int c = col[chunk0 + i], r = row[chunk0 + i];
        int b = c >> 9;
        int pos = atomicAdd(&cursor[b], 1);
        stage[pos] = ((unsigned)r << 9) | (unsigned)(c & (BN2 - 1));
    }
    __syncthreads();
    int wave = threadIdx.x >> 6, lane = threadIdx.x & 63, nw = blockDim.x >> 6;
    for (int b = wave; b < nb; b += nw) {
        int c = hist[b]; if (!c) continue;
        int s = excl[b], d = baseoff[b];
        for (int k = lane; k < c; k += WAVE) packed[d + k] = stage[s + k];
    }
}

// ---- pass 2: per-bucket sort by local node -> padded srcs, pse, dinv.
//      Per-node region padded to multiple of 16; pads point at row n (zeros).
//      Zero-degree nodes get pse=(0,0). Bucket regions via global cursor. ----
__global__ void __launch_bounds__(512)
sort_kernel(const int* __restrict__ bptr, const unsigned* __restrict__ packed,
            int* __restrict__ srcs, int2* __restrict__ pse,
            float* __restrict__ dinv, int* __restrict__ gpcur,
            int n, int nb, int E) {
    __shared__ int hist[BN2], pex[BN2], cur[BN2];
    __shared__ int pbase_s;
    int b = blockIdx.x;
    int start = bptr[b], end = bptr[b + 1];
    for (int i = threadIdx.x; i < BN2; i += blockDim.x) { hist[i] = 0; cur[i] = 0; }
    __syncthreads();
    for (int k = start + threadIdx.x; k < end; k += blockDim.x)
        atomicAdd(&hist[packed[k] & (BN2 - 1)], 1);
    __syncthreads();
    if (threadIdx.x < WAVE) {   // scan of PADDED degrees over 512 locals
        int lane = threadIdx.x, carry = 0;
#pragma unroll
        for (int base = 0; base < BN2; base += WAVE) {
            int i = base + lane;
            int pd = (hist[i] + 15) & ~15;
            int v = pd;
#pragma unroll
            for (int off = 1; off < WAVE; off <<= 1) {
                int t = __shfl_up(v, off, WAVE);
                if (lane >= off) v += t;
            }
            pex[i] = carry + v - pd;
            carry += __shfl(v, WAVE - 1, WAVE);
        }
        if (lane == 0) pbase_s = atomicAdd(gpcur, carry);
    }
    __syncthreads();
    int pbase = pbase_s;
    for (int i = threadIdx.x; i < BN2; i += blockDim.x) {
        int node = b * BN2 + i;
        if (node < n) {
            int d = hist[i], pd = (d + 15) & ~15;
            int ps = pbase + pex[i];
            pse[node]  = d ? make_int2(ps, ps + pd) : make_int2(0, 0);
            dinv[node] = d ? rsqrtf((float)d) : 0.f;
            for (int k = d; k < pd; ++k) srcs[ps + k] = n;   // dummy zero-row
        }
    }
    __syncthreads();
    for (int k = start + threadIdx.x; k < end; k += blockDim.x) {
        unsigned p = packed[k];
        int lc = p & (BN2 - 1);
        int pos = atomicAdd(&cur[lc], 1);
        srcs[pbase + pex[lc] + pos] = (int)(p >> 9);
    }
}

// ---- dense: h[n,OUTC] = fp16( (x[n,INC] @ W) * dinv[n] ).
//      Thread = 2 nodes x 4 j. W^T in LDS, stride INC+4 (conflict-free).
//      SPLIT: route cols 0-15 -> hlo, 16-31 -> hhi (16-wide fp16 rows). ----
template <int INC, int OUTC, int JT, bool SPLIT>
__global__ void __launch_bounds__(256, 4)
dense_kernel(const float* __restrict__ x, const float* __restrict__ W,
             const float* __restrict__ dinv, f16* __restrict__ hlo,
             f16* __restrict__ hhi, int n) {
    const int LSTR = INC + 4;
    const int SP   = 256 / JT;     // node slots (pairs) per block
    const int NT   = SP * 2;       // nodes per block
    __shared__ float Wt[OUTC * LSTR];
    for (int i = threadIdx.x; i < INC * OUTC; i += 256) {
        int k = i / OUTC, j = i % OUTC;
        Wt[j * LSTR + k] = W[i];
    }
    __syncthreads();
    const int jg = threadIdx.x % JT;
    const int sp = threadIdx.x / JT;
    int base = blockIdx.x * NT;
    int n0 = base + sp;
    int n1 = base + sp + SP;
    int n0c = n0 < n ? n0 : n - 1;   // clamp reads, guard writes
    int n1c = n1 < n ? n1 : n - 1;
    const float4* xr0 = (const float4*)(x + (size_t)n0c * INC);
    const float4* xr1 = (const float4*)(x + (size_t)n1c * INC);
    float a[2][4] = {{0.f, 0.f, 0.f, 0.f}, {0.f, 0.f, 0.f, 0.f}};
#pragma unroll 4
    for (int k4 = 0; k4 < INC / 4; ++k4) {
        float4 v0 = xr0[k4];
        float4 v1 = xr1[k4];
#pragma unroll
        for (int u = 0; u < 4; ++u) {
            float4 w = *(const float4*)(Wt + (jg + u * JT) * LSTR + 4 * k4);
            a[0][u] = fmaf(v0.x, w.x, fmaf(v0.y, w.y, fmaf(v0.z, w.z, fmaf(v0.w, w.w, a[0][u]))));
            a[1][u] = fmaf(v1.x, w.x, fmaf(v1.y, w.y, fmaf(v1.z, w.z, fmaf(v1.w, w.w, a[1][u]))));
        }
    }
#pragma unroll
    for (int pair = 0; pair < 2; ++pair) {
        int nn = pair ? n1 : n0;
        if (nn < n) {
            float d = dinv[nn];
#pragma unroll
            for (int u = 0; u < 4; ++u) {
                int c = jg + u * JT;
                f16* t;
                if (SPLIT) t = (c < 16) ? (hlo + (size_t)nn * 16 + c)
                               : (hhi + (size_t)nn * 16 + (c - 16));
                else       t = hlo + (size_t)nn * OUTC + c;
                *t = (f16)(a[pair][u] * d);
            }
        }
    }
}

// ---- aggregate: one wave per TWO nodes; 16 lanes cover one 32 B fp16 row;
//      8 gathers + 8 srcs issued per block-step, 2-block rotation -> up to
//      16 gathers + 8 srcs in flight; per-node mask/clamp, no tail.
//      Blocks [0,hg) use tlo/cols 0-15, [hg,2hg) use thi/cols 16-31. ----
template <bool RELU>
__global__ void __launch_bounds__(256)
csr_agg16x2_kernel(const int2* __restrict__ pse, const int* __restrict__ srcs,
                   const float* __restrict__ dinv, const f16* __restrict__ tlo,
                   const f16* __restrict__ thi, const float* __restrict__ bias,
                   float* __restrict__ out, int ostride, int hg, int n, int tailidx) {
    int bid = blockIdx.x;
    int pass = (bid >= hg) ? 1 : 0;
    const f16* hs = pass ? thi : tlo;
    int ocol = pass << 4;
    int bip = bid - pass * hg;
    int lane = threadIdx.x & 63;
    int wid  = threadIdx.x >> 6;
    int j  = lane & 15;
    int eo = lane >> 4;           // 0..3
    if (tailidx >= 0 && bid == 0 && threadIdx.x == 0) out[tailidx] = 0.f;
    int n0 = (bip * 4 + wid) * 2;
    if (n0 >= n) return;
    int n1 = n0 + 1;
    bool v1 = n1 < n;
    int4 se = *(const int4*)(pse + n0);      // pse[n0], pse[n1]
    int nb0 = (se.y - se.x) >> 4;
    int nb1 = v1 ? ((se.w - se.z) >> 4) : 0;
    float dv0 = dinv[n0];
    float dv1 = v1 ? dinv[n1] : 0.f;
    float bj = bias[ocol + j];
    size_t ob0 = (size_t)n0 * ostride + ocol + j;
    size_t ob1 = (size_t)n1 * ostride + ocol + j;
    int MAXB = nb0 > nb1 ? nb0 : nb1;
    if (MAXB == 0) {
        float v = bj;
        if (RELU) v = v > 0.f ? v : 0.f;
        if (eo == 0) out[ob0] = v;
        else if (eo == 1 && v1) out[ob1] = v;
        return;
    }
    const unsigned j2 = (unsigned)(j << 1);
    const char* hb = (const char*)hs;
    const int* p0 = srcs + se.x + eo;
    const int* p1 = srcs + se.z + eo;
    int nc0 = nb0 > 1 ? nb0 : 1;
    int nc1 = nb1 > 1 ? nb1 : 1;
    // prologue: block-0 srcs, block-0 gathers, block-1 srcs (clamped)
    int a0 = p0[0], a1 = p0[4], a2 = p0[8], a3 = p0[12];
    int a4 = p1[0], a5 = p1[4], a6 = p1[8], a7 = p1[12];
    f16 h0 = *(const f16*)(hb + (((unsigned)a0 << 5) + j2));
    f16 h1 = *(const f16*)(hb + (((unsigned)a1 << 5) + j2));
    f16 h2 = *(const f16*)(hb + (((unsigned)a2 << 5) + j2));
    f16 h3 = *(const f16*)(hb + (((unsigned)a3 << 5) + j2));
    f16 h4 = *(const f16*)(hb + (((unsigned)a4 << 5) + j2));
    f16 h5 = *(const f16*)(hb + (((unsigned)a5 << 5) + j2));
    f16 h6 = *(const f16*)(hb + (((unsigned)a6 << 5) + j2));
    f16 h7 = *(const f16*)(hb + (((unsigned)a7 << 5) + j2));
    const int* q0 = p0 + (nc0 > 1 ? 16 : 0);
    const int* q1 = p1 + (nc1 > 1 ? 16 : 0);
    int b0 = q0[0], b1 = q0[4], b2 = q0[8], b3 = q0[12];
    int b4 = q1[0], b5 = q1[4], b6 = q1[8], b7 = q1[12];
    float acc0 = 0.f, acc1 = 0.f, acc2 = 0.f, acc3 = 0.f;
    for (int b = 0; b < MAXB - 1; ++b) {
        // gathers for block b+1
        f16 g0 = *(const f16*)(hb + (((unsigned)b0 << 5) + j2));
        f16 g1 = *(const f16*)(hb + (((unsigned)b1 << 5) + j2));
        f16 g2 = *(const f16*)(hb + (((unsigned)b2 << 5) + j2));
        f16 g3 = *(const f16*)(hb + (((unsigned)b3 << 5) + j2));
        f16 g4 = *(const f16*)(hb + (((unsigned)b4 << 5) + j2));
        f16 g5 = *(const f16*)(hb + (((unsigned)b5 << 5) + j2));
        f16 g6 = *(const f16*)(hb + (((unsigned)b6 << 5) + j2));
        f16 g7 = *(const f16*)(hb + (((unsigned)b7 << 5) + j2));
        // srcs for block b+2 (clamped per node)
        int x0 = (b + 2) < nc0 ? (b + 2) : nc0 - 1;
        int x1 = (b + 2) < nc1 ? (b + 2) : nc1 - 1;
        const int* r0 = p0 + x0 * 16;
        const int* r1 = p1 + x1 * 16;
        int t0 = r0[0], t1 = r0[4], t2 = r0[8], t3 = r0[12];
        int t4 = r1[0], t5 = r1[4], t6 = r1[8], t7 = r1[12];
        // consume block b (masked per node)
        float m0 = b < nb0 ? 1.f : 0.f;
        float m1 = b < nb1 ? 1.f : 0.f;
        acc0 = fmaf(m0, (float)h0, acc0);
        acc1 = fmaf(m0, (float)h1, acc1);
        acc0 = fmaf(m0, (float)h2, acc0);
        acc1 = fmaf(m0, (float)h3, acc1);
        acc2 = fmaf(m1, (float)h4, acc2);
        acc3 = fmaf(m1, (float)h5, acc3);
        acc2 = fmaf(m1, (float)h6, acc2);
        acc3 = fmaf(m1, (float)h7, acc3);
        h0 = g0; h1 = g1; h2 = g2; h3 = g3;
        h4 = g4; h5 = g5; h6 = g6; h7 = g7;
        b0 = t0; b1 = t1; b2 = t2; b3 = t3;
        b4 = t4; b5 = t5; b6 = t6; b7 = t7;
    }
    {   // epilogue: block MAXB-1
        float m0 = (MAXB - 1) < nb0 ? 1.f : 0.f;
        float m1 = (MAXB - 1) < nb1 ? 1.f : 0.f;
        acc0 = fmaf(m0, (float)h0, acc0);
        acc1 = fmaf(m0, (float)h1, acc1);
        acc0 = fmaf(m0, (float)h2, acc0);
        acc1 = fmaf(m0, (float)h3, acc1);
        acc2 = fmaf(m1, (float)h4, acc2);
        acc3 = fmaf(m1, (float)h5, acc3);
        acc2 = fmaf(m1, (float)h6, acc2);
        acc3 = fmaf(m1, (float)h7, acc3);
    }
    float accA = acc0 + acc1;  // node0
    float accB = acc2 + acc3;  // node1
    accA += __shfl_xor(accA, 16, WAVE);
    accA += __shfl_xor(accA, 32, WAVE);
    accB += __shfl_xor(accB, 16, WAVE);
    accB += __shfl_xor(accB, 32, WAVE);
    if (eo == 0) {
        float v = accA * dv0 + bj;
        if (RELU) v = v > 0.f ? v : 0.f;
        out[ob0] = v;
    } else if (eo == 1 && v1) {
        float v = accB * dv1 + bj;
        if (RELU) v = v > 0.f ? v : 0.f;
        out[ob1] = v;
    }
}

extern "C" void kernel_launch(void* const* d_in, const int* in_sizes, int n_in,
                              void* d_out, int out_size, void* d_ws, size_t ws_size,
                              hipStream_t stream) {
    const float* x  = (const float*)d_in[0];
    const int*   ei = (const int*)d_in[1];    // harness converts int64 -> int32
    const float* W1 = (const float*)d_in[2];
    const float* b1 = (const float*)d_in[3];
    const float* W2 = (const float*)d_in[4];
    const float* b2 = (const float*)d_in[5];

    const int IN_C = 128, HID = 32, OC = 16;
    const int N = in_sizes[0] / IN_C;       // 100000
    const int E = in_sizes[1] / 2;          // 3200000
    const int* row = ei;
    const int* col = ei + E;
    const int NB = (N + BN2 - 1) / BN2;     // 196 coarse buckets

    char* base = (char*)d_ws;
    size_t off = 0;
    auto carve = [&](size_t bytes) -> char* {
        char* p = base + off;
        off = (off + bytes + 255) & ~(size_t)255;
        return p;
    };
    int*      gcnt  = (int*)     carve((size_t)NB * 4);
    int*      bptr  = (int*)     carve((size_t)(NB + 1) * 4);
    int*      gcur  = (int*)     carve((size_t)NB * 4);
    int*      gpcur = (int*)     carve(8);
    float*    dinv  = (float*)   carve((size_t)N * 4);
    int2*     pse   = (int2*)    carve((size_t)(N + 2) * 8);
    unsigned* packed= (unsigned*)carve((size_t)E * 4);
    int*      srcsP = (int*)     carve(((size_t)E + (size_t)N * 16 + 16) * 4); // padded + slack
    f16*      hlo   = (f16*)     carve((size_t)(N + 1) * 16 * 2);  // layer1 cols 0-15 (+zero row)
    f16*      hhi   = (f16*)     carve((size_t)(N + 1) * 16 * 2);  // layer1 cols 16-31
    f16*      h2t   = (f16*)     carve((size_t)(N + 1) * 16 * 2);  // layer2 table
    float*    bufB  = (float*)   carve((size_t)N * HID * 4);       // relu(agg1), fp32
    (void)ws_size; (void)n_in;

    float* outp = (float*)d_out;

    // build: 2-pass coarse radix sort by target node -> padded CSR + dinv
    hipMemsetAsync(gcnt, 0, (size_t)NB * 4, stream);
    bucket_count_kernel<<<512, 256, 0, stream>>>(col, gcnt, E, NB);
    bucket_scan_kernel<<<1, 64, 0, stream>>>(gcnt, bptr, gcur, NB, gpcur, hlo, hhi, h2t, N);
    partition_kernel<<<(E + CHUNK - 1) / CHUNK, 512, 0, stream>>>(row, col, gcur, packed, E, NB);
    sort_kernel<<<NB, 512, 0, stream>>>(bptr, packed, srcsP, pse, dinv, gpcur, N, NB, E);

    int npb = 8;                         // 4 waves x 2 nodes per block
    int g2  = (N + npb - 1) / npb;       // 12500 blocks per pass

    // layer 1: {hlo,hhi} = fp16((x@W1)*dinv) ; bufB = relu(dinv*agg + b1)
    {
        const int NT = (256 / 8) * 2;  // 64 nodes per block
        dense_kernel<128, 32, 8, true><<<(N + NT - 1) / NT, 256, 0, stream>>>(x, W1, dinv, hlo, hhi, N);
        csr_agg16x2_kernel<true><<<2 * g2, 256, 0, stream>>>(
            pse, srcsP, dinv, hlo, hhi, b1, bufB, HID, g2, N, -1);
    }
    // layer 2: h2t = fp16((bufB@W2)*dinv) ; out = dinv*agg(h2t) + b2
    {
        const int NT = (256 / 4) * 2;  // 128 nodes per block
        dense_kernel<32, 16, 4, false><<<(N + NT - 1) / NT, 256, 0, stream>>>(bufB, W2, dinv, h2t, nullptr, N);
        int tailidx = (out_size > N * OC) ? (N * OC) : -1;
        csr_agg16x2_kernel<false><<<g2, 256, 0, stream>>>(
            pse, srcsP, dinv, h2t, h2t, b2, outp, OC, g2, N, tailidx);
    }
}